// Round 3
// baseline (36.630 us; speedup 1.0000x reference)
//
#include <hip/hip_runtime.h>
#include <hip/hip_bf16.h>

// DecoderBlock: block-sparse masked linear (8 GEMMs M=256,N=1024,K=1024)
// + BatchNorm1d (batch stats; bias cancels exactly) + Swish.
// Pipeline: [conv] x f32->bf16 (4MB, L3-resident) ->
//           [gemm] 256 blocks = 8g x 8nt(N=128) x 4ksplit, bf16 LDS, MFMA,
//                  col-major bf16 partials ->
//           [bn]   per-feature stats over batch, swish, f32 out.
// XCD locality: g = blockIdx&7 puts each channel-group's blocks on one XCD;
// that XCD's L2 holds the whole x g-slice (512KB) across all its re-reads.

typedef float  f32x4  __attribute__((ext_vector_type(4)));
typedef short  short8 __attribute__((ext_vector_type(8)));
typedef unsigned short u16x8 __attribute__((ext_vector_type(8)));
typedef unsigned int   u32x2 __attribute__((ext_vector_type(2)));

static __device__ __forceinline__ unsigned short f2bf(float f) {
    unsigned int u = __float_as_uint(f);
    u += 0x7FFFu + ((u >> 16) & 1u);          // RNE (inputs finite)
    return (unsigned short)(u >> 16);
}
static __device__ __forceinline__ float bf2f(unsigned short h) {
    return __uint_as_float((unsigned int)h << 16);
}

#define GLL(gp, lp) __builtin_amdgcn_global_load_lds( \
    (const __attribute__((address_space(1))) unsigned int*)(gp), \
    (__attribute__((address_space(3))) unsigned int*)(lp), 16, 0, 0)

// ---------------- x f32 -> bf16 ----------------
__global__ __launch_bounds__(256) void conv_kernel(const float* __restrict__ x,
                                                   unsigned short* __restrict__ xb) {
    const int base = blockIdx.x * 1024 + threadIdx.x;
#pragma unroll
    for (int i = 0; i < 4; ++i) {
        const int cid = base + i * 256;               // 8-float chunk id
        const f32x4 a = *(const f32x4*)(x + (size_t)cid * 8);
        const f32x4 b = *(const f32x4*)(x + (size_t)cid * 8 + 4);
        u16x8 v;
        v[0] = f2bf(a[0]); v[1] = f2bf(a[1]); v[2] = f2bf(a[2]); v[3] = f2bf(a[3]);
        v[4] = f2bf(b[0]); v[5] = f2bf(b[1]); v[6] = f2bf(b[2]); v[7] = f2bf(b[3]);
        *(u16x8*)(xb + (size_t)cid * 8) = v;
    }
}

// ---------------- GEMM ----------------
// Block: M=256 x N=128, K-range=1024/s, BK=64. 4 waves stacked in M (64 rows each).
// LDS: A[256][64] bf16 row-major XOR-swizzled (chunk ^= row&7), staged via GLL with
// pre-swizzled SOURCE (both-sides involution); B[128][64] bf16 reg-staged+converted.
__global__ __launch_bounds__(256) void gemm_kernel(
    const unsigned short* __restrict__ xb, const float* __restrict__ W,
    unsigned short* __restrict__ P, int s)
{
    __shared__ __align__(16) char lds[98304];
    char* Abuf0 = lds;
    char* Abuf1 = lds + 32768;
    char* Bbuf0 = lds + 65536;
    char* Bbuf1 = lds + 81920;

    const int b  = blockIdx.x;
    const int g  = b & 7;                 // channel block -> XCD (round-robin dispatch)
    const int t2 = b >> 3;
    const int kh = t2 % s;
    const int nt = t2 / s;                // 0..7: N-tile of 128
    const int o  = g * 4 + (nt >> 1);
    const int f0 = (nt & 1) * 128;
    const int ksteps = 16 / s;
    const int kbase  = kh * (ksteps * 64);

    const int t    = threadIdx.x;
    const int wave = t >> 6;
    const int lane = t & 63;
    const int lr   = lane & 15;
    const int kq   = lane >> 4;

    f32x4 acc[4][8];
    const f32x4 zero = {0.f, 0.f, 0.f, 0.f};
#pragma unroll
    for (int i = 0; i < 4; ++i)
#pragma unroll
        for (int j = 0; j < 8; ++j) acc[i][j] = zero;

    f32x4 breg[4][2];

    auto STAGE_ISSUE = [&](int st, char* Ab) {
        const int kk = kbase + st * 64;
        const int cp = kk >> 8, kc = kk & 255;
        const unsigned short* asrc = xb + (size_t)(g * 1024 + kk);
#pragma unroll
        for (int i = 0; i < 8; ++i) {                       // A: 2048 chunks via GLL
            const int cid = i * 256 + t;
            const int r = cid >> 3, c = cid & 7;
            const int gc = c ^ (r & 7);                     // source pre-swizzle
            GLL(asrc + (size_t)r * 8192 + gc * 8, Ab + cid * 16);
        }
        const float* bsrc = W + ((size_t)((o * 32 + g * 4 + cp) * 256 + f0)) * 256 + kc;
#pragma unroll
        for (int i = 0; i < 4; ++i) {                       // B: f32 -> regs
            const int cid = i * 256 + t;
            const int n = cid >> 3, c = cid & 7;
            const float* p = bsrc + (size_t)n * 256 + c * 8;
            breg[i][0] = *(const f32x4*)p;
            breg[i][1] = *(const f32x4*)(p + 4);
        }
    };
    auto STAGE_WRITE = [&](char* Bb) {
#pragma unroll
        for (int i = 0; i < 4; ++i) {                       // convert + swizzled write
            const int cid = i * 256 + t;
            const int n = cid >> 3, c = cid & 7;
            short8 v;
            v[0] = (short)f2bf(breg[i][0][0]); v[1] = (short)f2bf(breg[i][0][1]);
            v[2] = (short)f2bf(breg[i][0][2]); v[3] = (short)f2bf(breg[i][0][3]);
            v[4] = (short)f2bf(breg[i][1][0]); v[5] = (short)f2bf(breg[i][1][1]);
            v[6] = (short)f2bf(breg[i][1][2]); v[7] = (short)f2bf(breg[i][1][3]);
            *(short8*)(Bb + n * 128 + ((c ^ (n & 7)) * 16)) = v;
        }
    };
    auto COMPUTE = [&](const char* Ab, const char* Bb) {
#pragma unroll
        for (int ks = 0; ks < 2; ++ks) {
            short8 af[4], bfr[8];
#pragma unroll
            for (int i = 0; i < 4; ++i) {
                const int r = wave * 64 + i * 16 + lr;
                af[i] = *(const short8*)(Ab + r * 128 + (((ks * 4 + kq) ^ (r & 7)) * 16));
            }
#pragma unroll
            for (int j = 0; j < 8; ++j) {
                const int n = j * 16 + lr;
                bfr[j] = *(const short8*)(Bb + n * 128 + (((ks * 4 + kq) ^ (n & 7)) * 16));
            }
#pragma unroll
            for (int i = 0; i < 4; ++i)
#pragma unroll
                for (int j = 0; j < 8; ++j)
                    acc[i][j] = __builtin_amdgcn_mfma_f32_16x16x32_bf16(af[i], bfr[j], acc[i][j], 0, 0, 0);
        }
    };

    STAGE_ISSUE(0, Abuf0);
    asm volatile("s_waitcnt vmcnt(0)" ::: "memory");
    STAGE_WRITE(Bbuf0);
    __syncthreads();
    for (int st = 0; st < ksteps; ++st) {
        char* Ac = (st & 1) ? Abuf1 : Abuf0;
        char* Bc = (st & 1) ? Bbuf1 : Bbuf0;
        char* An = (st & 1) ? Abuf0 : Abuf1;
        char* Bn = (st & 1) ? Bbuf0 : Bbuf1;
        if (st + 1 < ksteps) STAGE_ISSUE(st + 1, An);
        COMPUTE(Ac, Bc);
        if (st + 1 < ksteps) {
            asm volatile("s_waitcnt vmcnt(0)" ::: "memory");
            STAGE_WRITE(Bn);
        }
        __syncthreads();
    }

    // epilogue: C/D layout col = lane&15, row = (lane>>4)*4 + reg.
    // Partials COL-MAJOR [8192 feat][256 batch] bf16: lane packs its 4 rows -> 8B store.
    unsigned short* Psp = P + (size_t)kh * 2097152;
#pragma unroll
    for (int i = 0; i < 4; ++i) {
        const int row0 = wave * 64 + i * 16 + kq * 4;
#pragma unroll
        for (int j = 0; j < 8; ++j) {
            const int gc = g * 1024 + nt * 128 + j * 16 + lr;
            u32x2 d;
            d[0] = (unsigned int)f2bf(acc[i][j][0]) | ((unsigned int)f2bf(acc[i][j][1]) << 16);
            d[1] = (unsigned int)f2bf(acc[i][j][2]) | ((unsigned int)f2bf(acc[i][j][3]) << 16);
            *(u32x2*)(Psp + (size_t)gc * 256 + row0) = d;
        }
    }
}

// ---------------- BN (batch stats) + Swish ----------------
// 256 blocks x 32 features. Col-major partials -> 512B contiguous per feature.
__global__ __launch_bounds__(256) void bn_kernel(
    const unsigned short* __restrict__ P,
    const float* __restrict__ gamma, const float* __restrict__ beta,
    float* __restrict__ out, int s)
{
    __shared__ float ytile[256][33];     // [row][col], stride 33 breaks bank patterns
    __shared__ float ssum[32], ssq[32], sa[32], sb[32];

    const int c0 = blockIdx.x * 32;
    const int t  = threadIdx.x;
    const int cl = t >> 3, q = t & 7;    // 8 threads per feature column

    float s1 = 0.f, s2 = 0.f;
    const unsigned short* pc = P + (size_t)(c0 + cl) * 256;
#pragma unroll
    for (int p = 0; p < 4; ++p) {
        const int chunk = q + 8 * p;     // 8 rows per chunk
        float a[8];
#pragma unroll
        for (int e = 0; e < 8; ++e) a[e] = 0.f;
        for (int ksp = 0; ksp < s; ++ksp) {
            const u16x8 v = *(const u16x8*)(pc + (size_t)ksp * 2097152 + chunk * 8);
#pragma unroll
            for (int e = 0; e < 8; ++e) a[e] += bf2f(v[e]);
        }
#pragma unroll
        for (int e = 0; e < 8; ++e) {
            s1 += a[e]; s2 += a[e] * a[e];
            ytile[chunk * 8 + e][cl] = a[e];
        }
    }
    s1 += __shfl_xor(s1, 1); s2 += __shfl_xor(s2, 1);
    s1 += __shfl_xor(s1, 2); s2 += __shfl_xor(s2, 2);
    s1 += __shfl_xor(s1, 4); s2 += __shfl_xor(s2, 4);
    if (q == 0) { ssum[cl] = s1; ssq[cl] = s2; }
    __syncthreads();
    if (t < 32) {
        const float mean = ssum[t] * (1.0f / 256.0f);
        const float var  = ssq[t] * (1.0f / 256.0f) - mean * mean;   // biased (jnp.var)
        const float istd = rsqrtf(var + 1e-5f);
        const float ga = gamma[c0 + t];
        sa[t] = ga * istd;
        sb[t] = beta[c0 + t] - mean * ga * istd;
    }
    __syncthreads();
    const int rq = t >> 3, cq = q * 4;
#pragma unroll
    for (int rp = 0; rp < 8; ++rp) {
        const int r = rp * 32 + rq;
        float4 ov;
        { const float z = sa[cq+0] * ytile[r][cq+0] + sb[cq+0]; ov.x = z / (1.0f + expf(-z)); }
        { const float z = sa[cq+1] * ytile[r][cq+1] + sb[cq+1]; ov.y = z / (1.0f + expf(-z)); }
        { const float z = sa[cq+2] * ytile[r][cq+2] + sb[cq+2]; ov.z = z / (1.0f + expf(-z)); }
        { const float z = sa[cq+3] * ytile[r][cq+3] + sb[cq+3]; ov.w = z / (1.0f + expf(-z)); }
        *(float4*)(out + (size_t)r * 8192 + c0 + cq) = ov;
    }
}

extern "C" void kernel_launch(void* const* d_in, const int* in_sizes, int n_in,
                              void* d_out, int out_size, void* d_ws, size_t ws_size,
                              hipStream_t stream) {
    const float* x     = (const float*)d_in[0];
    const float* W     = (const float*)d_in[1];
    // d_in[2] = bias: cancelled exactly by BN mean subtraction -> unused
    const float* gamma = (const float*)d_in[3];
    const float* beta  = (const float*)d_in[4];
    // d_in[5] = mask: implicit in block structure -> unused
    float* out = (float*)d_out;

    unsigned short* xb = (unsigned short*)d_ws;        // 4MB bf16 x
    unsigned short* P  = xb + 2097152;                 // s x 4MB bf16 partials

    int s;
    if      (ws_size >= 20u * 1048576u) s = 4;
    else if (ws_size >= 12u * 1048576u) s = 2;
    else                                s = 1;         // needs 8MB

    conv_kernel<<<256, 256, 0, stream>>>(x, xb);
    gemm_kernel<<<64 * s, 256, 0, stream>>>(xb, W, P, s);
    bn_kernel<<<256, 256, 0, stream>>>(P, gamma, beta, out, s);
}

// Round 4
// 26.316 us; speedup vs baseline: 1.3919x; 1.3919x over previous
//
#include <hip/hip_runtime.h>
#include <hip/hip_bf16.h>

// DecoderBlock: block-sparse masked linear (8 GEMMs M=256,N=1024,K=1024)
// + BatchNorm1d (batch stats; bias cancels exactly under mean-subtract) + Swish.
// FUSED: each block owns full batch (M=256) x 32 features -> BN stats are
// block-local; GEMM + BN + Swish in one kernel, no intermediate in HBM.
// grid 256 = 8 g x 32 nt; g = bid&7 -> all 32 blocks of channel-group g land
// on XCD g (round-robin dispatch), its L2 serves g's 512KB bf16 x-slice.

typedef float  f32x4  __attribute__((ext_vector_type(4)));
typedef short  short8 __attribute__((ext_vector_type(8)));
typedef unsigned short u16x8 __attribute__((ext_vector_type(8)));

static __device__ __forceinline__ unsigned short f2bf(float f) {
    unsigned int u = __float_as_uint(f);
    u += 0x7FFFu + ((u >> 16) & 1u);          // RNE (inputs finite)
    return (unsigned short)(u >> 16);
}
static __device__ __forceinline__ float bf2f(unsigned short h) {
    return __uint_as_float((unsigned int)h << 16);
}

#define GLL(gp, lp) __builtin_amdgcn_global_load_lds( \
    (const __attribute__((address_space(1))) unsigned int*)(gp), \
    (__attribute__((address_space(3))) unsigned int*)(lp), 16, 0, 0)

// ---------------- x f32 -> bf16 (4MB, L2/L3-resident afterwards) ----------------
__global__ __launch_bounds__(256) void conv_kernel(const float* __restrict__ x,
                                                   unsigned short* __restrict__ xb) {
    const int base = blockIdx.x * 1024 + threadIdx.x;
#pragma unroll
    for (int i = 0; i < 4; ++i) {
        const int cid = base + i * 256;               // 8-float chunk id
        const f32x4 a = *(const f32x4*)(x + (size_t)cid * 8);
        const f32x4 b = *(const f32x4*)(x + (size_t)cid * 8 + 4);
        u16x8 v;
        v[0] = f2bf(a[0]); v[1] = f2bf(a[1]); v[2] = f2bf(a[2]); v[3] = f2bf(a[3]);
        v[4] = f2bf(b[0]); v[5] = f2bf(b[1]); v[6] = f2bf(b[2]); v[7] = f2bf(b[3]);
        *(u16x8*)(xb + (size_t)cid * 8) = v;
    }
}

// ---------------- fused GEMM + BN + Swish ----------------
// Block: M=256 x N=32, K=1024, BK=64 (16 steps). 4 waves stacked in M (64 rows).
// A: [256][64] bf16 LDS, triple-buffered, GLL with source pre-swizzle (c ^= r&7).
// B: [32][64] bf16 LDS, double-buffered, reg-staged f32->bf16, swizzled ds_write.
// Pipeline: issue st+2, counted s_waitcnt vmcnt(10), raw s_barrier (no drain).
__global__ __launch_bounds__(256) void fused_kernel(
    const unsigned short* __restrict__ xb, const float* __restrict__ W,
    const float* __restrict__ gamma, const float* __restrict__ beta,
    float* __restrict__ out)
{
    __shared__ __align__(16) char ldsA[3][32768];
    __shared__ __align__(16) char ldsB[2][4096];
    __shared__ float wps1[4][32], wps2[4][32];
    __shared__ float sa[32], sb[32];

    const int bid = blockIdx.x;
    const int g   = bid & 7;               // channel group -> XCD
    const int nt  = bid >> 3;              // 0..31
    const int o   = g * 4 + (nt >> 3);
    const int f0  = (nt & 7) * 32;
    const int gcol0 = o * 256 + f0;        // global feature col of this block's 32 cols

    const int t    = threadIdx.x;
    const int wave = t >> 6;
    const int lane = t & 63;
    const int lr   = lane & 15;
    const int kq   = lane >> 4;

    f32x4 acc[4][2];
    const f32x4 zero = {0.f, 0.f, 0.f, 0.f};
#pragma unroll
    for (int i = 0; i < 4; ++i) { acc[i][0] = zero; acc[i][1] = zero; }

    f32x4 breg[2][2];

    auto ISSUE = [&](int st) {             // stage step st: A via GLL, B f32 -> regs
        const int kk = st * 64;
        const unsigned short* asrc = xb + g * 1024 + kk;
        char* Ab = ldsA[st % 3];
#pragma unroll
        for (int i = 0; i < 8; ++i) {
            const int cid = i * 256 + t;
            const int r = cid >> 3, c = cid & 7;
            GLL(asrc + (size_t)r * 8192 + (c ^ (r & 7)) * 8, Ab + cid * 16);
        }
        const int cp = st >> 2, kc = (st & 3) * 64;
        const float* bsrc = W + ((size_t)((o * 32 + g * 4 + cp) * 256 + f0)) * 256 + kc
                              + (size_t)(t >> 3) * 256 + (t & 7) * 8;
        breg[st & 1][0] = *(const f32x4*)bsrc;
        breg[st & 1][1] = *(const f32x4*)(bsrc + 4);
    };
    auto WRITEB = [&](int st) {            // convert + swizzled ds_write
        const int n = t >> 3, c = t & 7;
        short8 v;
        v[0] = (short)f2bf(breg[st & 1][0][0]); v[1] = (short)f2bf(breg[st & 1][0][1]);
        v[2] = (short)f2bf(breg[st & 1][0][2]); v[3] = (short)f2bf(breg[st & 1][0][3]);
        v[4] = (short)f2bf(breg[st & 1][1][0]); v[5] = (short)f2bf(breg[st & 1][1][1]);
        v[6] = (short)f2bf(breg[st & 1][1][2]); v[7] = (short)f2bf(breg[st & 1][1][3]);
        *(short8*)(ldsB[st & 1] + n * 128 + ((c ^ (n & 7)) * 16)) = v;
    };
    auto COMPUTE = [&](int st) {
        const char* Ab = ldsA[st % 3];
        const char* Bb = ldsB[st & 1];
#pragma unroll
        for (int ks = 0; ks < 2; ++ks) {
            short8 af[4], bfr[2];
#pragma unroll
            for (int i = 0; i < 4; ++i) {
                const int ra = wave * 64 + i * 16 + lr;
                af[i] = *(const short8*)(Ab + ra * 128 + (((ks * 4 + kq) ^ (ra & 7)) * 16));
            }
#pragma unroll
            for (int j = 0; j < 2; ++j) {
                const int n = j * 16 + lr;
                bfr[j] = *(const short8*)(Bb + n * 128 + (((ks * 4 + kq) ^ (n & 7)) * 16));
            }
#pragma unroll
            for (int i = 0; i < 4; ++i)
#pragma unroll
                for (int j = 0; j < 2; ++j)
                    acc[i][j] = __builtin_amdgcn_mfma_f32_16x16x32_bf16(af[i], bfr[j], acc[i][j], 0, 0, 0);
        }
    };

    // prologue
    ISSUE(0);
    ISSUE(1);
    asm volatile("s_waitcnt vmcnt(10)" ::: "memory");   // step-0 A+B landed
    WRITEB(0);
    asm volatile("s_waitcnt lgkmcnt(0)" ::: "memory");
    __builtin_amdgcn_s_barrier();

#pragma unroll
    for (int st = 0; st < 16; ++st) {
        COMPUTE(st);
        if (st < 14) {
            ISSUE(st + 2);
            asm volatile("s_waitcnt vmcnt(10)" ::: "memory");  // st+1 landed, st+2 in flight
            WRITEB(st + 1);
            asm volatile("s_waitcnt lgkmcnt(0)" ::: "memory");
            __builtin_amdgcn_s_barrier();
        } else if (st == 14) {
            asm volatile("s_waitcnt vmcnt(0)" ::: "memory");   // drain step-15 loads
            WRITEB(15);
            asm volatile("s_waitcnt lgkmcnt(0)" ::: "memory");
            __builtin_amdgcn_s_barrier();
        }
    }

    // ---------------- fused BN + Swish epilogue ----------------
    // per-lane column sums over the lane's 16 rows x 2 cols
    float s1[2] = {0.f, 0.f}, s2[2] = {0.f, 0.f};
#pragma unroll
    for (int i = 0; i < 4; ++i)
#pragma unroll
        for (int j = 0; j < 2; ++j)
#pragma unroll
            for (int r = 0; r < 4; ++r) {
                const float v = acc[i][j][r];
                s1[j] += v; s2[j] += v * v;
            }
    // reduce across kq groups (lanes sharing lr): xor 16, 32
#pragma unroll
    for (int j = 0; j < 2; ++j) {
        s1[j] += __shfl_xor(s1[j], 16); s2[j] += __shfl_xor(s2[j], 16);
        s1[j] += __shfl_xor(s1[j], 32); s2[j] += __shfl_xor(s2[j], 32);
    }
    if (kq == 0) {
#pragma unroll
        for (int j = 0; j < 2; ++j) {
            wps1[wave][j * 16 + lr] = s1[j];
            wps2[wave][j * 16 + lr] = s2[j];
        }
    }
    __syncthreads();
    if (t < 32) {
        float a1 = wps1[0][t] + wps1[1][t] + wps1[2][t] + wps1[3][t];
        float a2 = wps2[0][t] + wps2[1][t] + wps2[2][t] + wps2[3][t];
        const float mean = a1 * (1.0f / 256.0f);
        const float var  = a2 * (1.0f / 256.0f) - mean * mean;   // biased (jnp.var)
        const float istd = rsqrtf(var + 1e-5f);
        const float ga = gamma[gcol0 + t];
        sa[t] = ga * istd;
        sb[t] = beta[gcol0 + t] - mean * ga * istd;
    }
    __syncthreads();

    // apply affine + swish, write out (C/D layout: col=lane&15, row=(lane>>4)*4+reg)
#pragma unroll
    for (int i = 0; i < 4; ++i) {
        const int row0 = wave * 64 + i * 16 + kq * 4;
#pragma unroll
        for (int j = 0; j < 2; ++j) {
            const int col = j * 16 + lr;
            const float a = sa[col], b2 = sb[col];
#pragma unroll
            for (int r = 0; r < 4; ++r) {
                const float z = a * acc[i][j][r] + b2;
                out[(size_t)(row0 + r) * 8192 + gcol0 + col] = z / (1.0f + expf(-z));
            }
        }
    }
}

extern "C" void kernel_launch(void* const* d_in, const int* in_sizes, int n_in,
                              void* d_out, int out_size, void* d_ws, size_t ws_size,
                              hipStream_t stream) {
    const float* x     = (const float*)d_in[0];
    const float* W     = (const float*)d_in[1];
    // d_in[2] = bias: cancelled exactly by BN mean subtraction -> unused
    const float* gamma = (const float*)d_in[3];
    const float* beta  = (const float*)d_in[4];
    // d_in[5] = mask: implicit in block structure -> unused
    float* out = (float*)d_out;

    unsigned short* xb = (unsigned short*)d_ws;   // 4MB bf16 x

    conv_kernel<<<256, 256, 0, stream>>>(x, xb);
    fused_kernel<<<256, 256, 0, stream>>>(xb, W, gamma, beta, out);
}